// Round 4
// baseline (1602.199 us; speedup 1.0000x reference)
//
#include <hip/hip_runtime.h>
#include <stdint.h>

typedef unsigned short u16;
typedef __attribute__((ext_vector_type(8))) short short8;
typedef __attribute__((ext_vector_type(4))) short short4v;
typedef __attribute__((ext_vector_type(4))) float f32x4;
typedef __attribute__((ext_vector_type(4))) unsigned int u32x4;

__device__ __forceinline__ u16 f2bf(float f) {
  union { float f; uint32_t i; } v; v.f = f;
  uint32_t x = v.i;
  return (u16)((x + 0x7fffu + ((x >> 16) & 1u)) >> 16);  // RNE
}
__device__ __forceinline__ float bf2f(u16 u) {
  union { uint32_t i; float f; } v; v.i = ((uint32_t)u) << 16; return v.f;
}

// fp32 -> bf16 convert (weights)
__global__ __launch_bounds__(256) void cvt_kernel(const float* __restrict__ src,
                                                  u16* __restrict__ dst, int n) {
  int i = blockIdx.x * 256 + threadIdx.x;
  if (i < n) dst[i] = f2bf(src[i]);
}

// stable top-8-smallest insert (strict < keeps earlier index on ties, matching top_k)
__device__ __forceinline__ void top8_insert(float (&td)[8], int (&ti)[8], float d, int idx) {
  if (d < td[7]) {
#pragma unroll
    for (int j = 7; j >= 1; --j) {
      bool c1 = d < td[j - 1];
      bool c2 = d < td[j];
      td[j] = c1 ? td[j - 1] : (c2 ? d : td[j]);
      ti[j] = c1 ? ti[j - 1] : (c2 ? idx : ti[j]);
    }
    if (d < td[0]) { td[0] = d; ti[0] = idx; }
  }
}

// ---------------- KNN level2 -> level1 : x1 = concat(l1_cls_feat, interp192) as bf16 ----------------
__global__ __launch_bounds__(64) void knn_small_kernel(
    const float* __restrict__ l1_to_l2,  // [4,512,2048] fp32
    const float* __restrict__ l2feat,    // [4,512,192]  fp32
    const float* __restrict__ l1feat,    // [4,2048,128] fp32
    u16* __restrict__ x1)                // [4*2048, 320] bf16
{
  const int lane = threadIdx.x;
  const int b = blockIdx.x >> 5;
  const int base = (blockIdx.x & 31) << 6;

  float td[8]; int ti[8];
#pragma unroll
  for (int j = 0; j < 8; ++j) { td[j] = 3.0e38f; ti[j] = 0; }

  const float* dp = l1_to_l2 + (size_t)b * 512 * 2048 + base + lane;
#pragma unroll 4
  for (int n2 = 0; n2 < 512; ++n2) {
    float d = *dp;
    dp += 2048;
    top8_insert(td, ti, d, n2);
  }

  float w[8], s = 0.f;
#pragma unroll
  for (int j = 0; j < 8; ++j) { w[j] = 1.f / (td[j] + 1e-8f); s += w[j]; }
  const float inv = 1.f / (s + 1e-8f);

  __shared__ float ws[64][8];
  __shared__ int   is_[64][8];
#pragma unroll
  for (int j = 0; j < 8; ++j) { ws[lane][j] = w[j] * inv; is_[lane][j] = ti[j]; }
  __syncthreads();

  const float* l2b = l2feat + (size_t)b * 512 * 192;
  for (int p2 = 0; p2 < 64; ++p2) {
    float a0 = 0.f, a1 = 0.f, a2 = 0.f;
#pragma unroll
    for (int j = 0; j < 8; ++j) {
      const float wj = ws[p2][j];
      const float* frp = l2b + (size_t)is_[p2][j] * 192;
      a0 += wj * frp[lane];
      a1 += wj * frp[lane + 64];
      a2 += wj * frp[lane + 128];
    }
    const int row = b * 2048 + base + p2;
    u16* xr = x1 + (size_t)row * 320;
    const float* lf = l1feat + (size_t)row * 128;
    xr[lane] = f2bf(lf[lane]);
    xr[64 + lane] = f2bf(lf[64 + lane]);
    xr[128 + lane] = f2bf(a0);
    xr[192 + lane] = f2bf(a1);
    xr[256 + lane] = f2bf(a2);
  }
}

// ---------------- KNN level1 -> level0 : xcat = concat(radar64, interp640) as bf16 ----------------
__global__ __launch_bounds__(128) void knn_big_kernel(
    const float* __restrict__ dist,   // [4,2048,8192] fp32
    const u16* __restrict__ f,        // [4*2048,640] bf16
    const float* __restrict__ radar,  // [4,8192,64] fp32
    u16* __restrict__ xcat)           // [4*8192,704] bf16
{
  const int t = threadIdx.x;
  const int lane = t & 63;
  const int half = t >> 6;
  const int b = blockIdx.x >> 7;
  const int base = (blockIdx.x & 127) << 6;

  float td[8]; int ti[8];
#pragma unroll
  for (int j = 0; j < 8; ++j) { td[j] = 3.0e38f; ti[j] = 0; }

  const float* dp = dist + (size_t)b * 2048 * 8192 + (size_t)(half * 1024) * 8192 + base + lane;
  const int ib0 = half * 1024;
#pragma unroll 4
  for (int n1 = 0; n1 < 1024; ++n1) {
    float d = *dp;
    dp += 8192;
    top8_insert(td, ti, d, ib0 + n1);
  }

  __shared__ float sd[128][8];
  __shared__ int   si[128][8];
  __shared__ float ws[64][8];
  __shared__ int   is_[64][8];
#pragma unroll
  for (int j = 0; j < 8; ++j) { sd[t][j] = td[j]; si[t][j] = ti[j]; }
  __syncthreads();

  if (t < 64) {
    // merge two sorted 8-lists; first half has lower n1 indices -> <= keeps stability
    float md[8]; int mi[8];
    int ia = 0, ib = 0;
#pragma unroll
    for (int r = 0; r < 8; ++r) {
      float da = sd[t][ia], db2 = sd[t + 64][ib];
      bool ta = da <= db2;
      md[r] = ta ? da : db2;
      mi[r] = ta ? si[t][ia] : si[t + 64][ib];
      if (ta) ++ia; else ++ib;
    }
    float w[8], s = 0.f;
#pragma unroll
    for (int j = 0; j < 8; ++j) { w[j] = 1.f / (md[j] + 1e-8f); s += w[j]; }
    const float inv = 1.f / (s + 1e-8f);
#pragma unroll
    for (int j = 0; j < 8; ++j) { ws[t][j] = w[j] * inv; is_[t][j] = mi[j]; }
  }
  __syncthreads();

  const u16* fb = f + (size_t)b * 2048 * 640;
  for (int p2 = 0; p2 < 64; ++p2) {
    float acc[5] = {0.f, 0.f, 0.f, 0.f, 0.f};
#pragma unroll
    for (int j = 0; j < 8; ++j) {
      const float wj = ws[p2][j];
      const u16* frp = fb + (size_t)is_[p2][j] * 640;
#pragma unroll
      for (int s5 = 0; s5 < 5; ++s5)
        acc[s5] += wj * bf2f(frp[t + s5 * 128]);
    }
    const int row = b * 8192 + base + p2;
    u16* xr = xcat + (size_t)row * 704;
    if (t < 64) xr[t] = f2bf(radar[(size_t)row * 64 + t]);
#pragma unroll
    for (int s5 = 0; s5 < 5; ++s5)
      xr[64 + s5 * 128 + t] = f2bf(acc[s5]);
  }
}

// ---------------- fused GEMM + bias + BN(eval) + ReLU ----------------
// C[m,n] = relu(g[m]*inv_sqrt*(sum_k W[m,k]*X[n,k] + b[m]) + be[m])
// W:[M,K] bf16 k-fast, X:[Ntot,K] bf16 k-fast. bias/gamma/beta fp32.
// OUT_MODE 0: bf16 Y[n*M+m]; OUT_MODE 1: fp32 Y[b*M*8192+m*8192+(n%8192)]
#define BM 128
#define BN 128
#define BK 32

template <int OUT_MODE>
__global__ __launch_bounds__(256) void gemm_bf16(
    const u16* __restrict__ W, const u16* __restrict__ X,
    const float* __restrict__ bias, const float* __restrict__ gamma, const float* __restrict__ beta,
    void* __restrict__ Yv, int M, int K, int Ntot)
{
  __shared__ u16 As[BM * BK];
  __shared__ u16 Bs[BN * BK];

  const int t = threadIdx.x;
  const int lane = t & 63;
  const int wv = t >> 6;
  const int mtiles = M >> 7;
  const int mt = (int)blockIdx.x % mtiles;
  const int nt = (int)blockIdx.x / mtiles;
  const int m0 = mt << 7;
  const int n0 = nt << 7;
  const int fr = lane & 15;
  const int quad = lane >> 4;
  const int wr = (wv >> 1) << 6;  // wave m-offset within tile
  const int wc = (wv & 1) << 6;   // wave n-offset within tile

  const f32x4 zero = {0.f, 0.f, 0.f, 0.f};
  f32x4 acc[4][4];
#pragma unroll
  for (int i = 0; i < 4; ++i)
#pragma unroll
    for (int j = 0; j < 4; ++j) acc[i][j] = zero;

  // staging: 512 chunks of 16B per tile; chunk c -> row c/4, k8 (c%4)*8
  const int c0 = (wv << 6) + lane;
  const int c1 = c0 + 256;
  const u16* Wp0 = W + (size_t)(m0 + (c0 >> 2)) * K + ((c0 & 3) << 3);
  const u16* Wp1 = W + (size_t)(m0 + (c1 >> 2)) * K + ((c1 & 3) << 3);
  const u16* Xp0 = X + (size_t)(n0 + (c0 >> 2)) * K + ((c0 & 3) << 3);
  const u16* Xp1 = X + (size_t)(n0 + (c1 >> 2)) * K + ((c1 & 3) << 3);

  for (int k0 = 0; k0 < K; k0 += BK) {
    u32x4 wa = *(const u32x4*)(Wp0 + k0);
    u32x4 wb = *(const u32x4*)(Wp1 + k0);
    u32x4 xa = *(const u32x4*)(Xp0 + k0);
    u32x4 xb = *(const u32x4*)(Xp1 + k0);
    __syncthreads();  // all waves done reading previous tile
    *(u32x4*)(As + (c0 << 3)) = wa;
    *(u32x4*)(As + (c1 << 3)) = wb;
    *(u32x4*)(Bs + (c0 << 3)) = xa;
    *(u32x4*)(Bs + (c1 << 3)) = xb;
    __syncthreads();  // stores visible

    short8 af[4], bfv[4];
#pragma unroll
    for (int i = 0; i < 4; ++i)
      af[i] = *(const short8*)(As + (wr + i * 16 + fr) * BK + (quad << 3));
#pragma unroll
    for (int j = 0; j < 4; ++j)
      bfv[j] = *(const short8*)(Bs + (wc + j * 16 + fr) * BK + (quad << 3));
#pragma unroll
    for (int i = 0; i < 4; ++i)
#pragma unroll
      for (int j = 0; j < 4; ++j)
        acc[i][j] = __builtin_amdgcn_mfma_f32_16x16x32_bf16(af[i], bfv[j], acc[i][j], 0, 0, 0);
  }

  // epilogue: C/D layout col=lane&15 (n), row=quad*4+r (m)
  constexpr float BNS = 0.99999500003749968f;  // 1/sqrt(1+1e-5)
#pragma unroll
  for (int i = 0; i < 4; ++i) {
    const int mb = m0 + wr + i * 16 + (quad << 2);
    float g0[4], b0[4], e0[4];
#pragma unroll
    for (int r = 0; r < 4; ++r) {
      g0[r] = gamma[mb + r] * BNS;
      b0[r] = bias[mb + r];
      e0[r] = beta[mb + r];
    }
#pragma unroll
    for (int j = 0; j < 4; ++j) {
      const int n = n0 + wc + j * 16 + fr;
      if (OUT_MODE == 0) {
        u16* Y = (u16*)Yv;
        short4v sv;
#pragma unroll
        for (int r = 0; r < 4; ++r) {
          float v = g0[r] * (acc[i][j][r] + b0[r]) + e0[r];
          sv[r] = (short)f2bf(fmaxf(v, 0.f));
        }
        *(short4v*)(Y + (size_t)n * M + mb) = sv;
      } else {
        float* Y = (float*)Yv;
        const int bb = n >> 13, nn = n & 8191;
        float* yp = Y + ((size_t)bb * M + mb) * 8192 + nn;
#pragma unroll
        for (int r = 0; r < 4; ++r) {
          float v = g0[r] * (acc[i][j][r] + b0[r]) + e0[r];
          yp[(size_t)r * 8192] = fmaxf(v, 0.f);
        }
      }
    }
  }
}

extern "C" void kernel_launch(void* const* d_in, const int* in_sizes, int n_in,
                              void* d_out, int out_size, void* d_ws, size_t ws_size,
                              hipStream_t stream) {
  (void)in_sizes; (void)n_in; (void)out_size; (void)ws_size;
  const float* radar    = (const float*)d_in[0];   // [4,8192,64]
  const float* l1feat   = (const float*)d_in[1];   // [4,2048,128]
  const float* l2feat   = (const float*)d_in[2];   // [4,512,192]
  const float* l0_to_l1 = (const float*)d_in[3];   // [4,2048,8192]
  const float* l1_to_l2 = (const float*)d_in[4];   // [4,512,2048]
  const float* w21a = (const float*)d_in[5];
  const float* b21a = (const float*)d_in[6];
  const float* g21a = (const float*)d_in[7];
  const float* be21a = (const float*)d_in[8];
  const float* w21b = (const float*)d_in[9];
  const float* b21b = (const float*)d_in[10];
  const float* g21b = (const float*)d_in[11];
  const float* be21b = (const float*)d_in[12];
  const float* w10a = (const float*)d_in[13];
  const float* b10a = (const float*)d_in[14];
  const float* g10a = (const float*)d_in[15];
  const float* be10a = (const float*)d_in[16];
  const float* w10b = (const float*)d_in[17];
  const float* b10b = (const float*)d_in[18];
  const float* g10b = (const float*)d_in[19];
  const float* be10b = (const float*)d_in[20];

  u16* x1   = (u16*)d_ws;                       // [8192,320]
  u16* h1   = x1 + (size_t)8192 * 320;          // [8192,640]
  u16* fbuf = h1 + (size_t)8192 * 640;          // [8192,640]
  u16* xcat = fbuf + (size_t)8192 * 640;        // [32768,704]
  u16* h2   = xcat + (size_t)32768 * 704;       // [32768,640]
  u16* wb21a = h2 + (size_t)32768 * 640;        // [640,320]
  u16* wb21b = wb21a + 640 * 320;               // [640,640]
  u16* wb10a = wb21b + 640 * 640;               // [640,704]
  u16* wb10b = wb10a + 640 * 704;               // [768,640]
  // total ~117 MB of workspace

  cvt_kernel<<<(640 * 320 + 255) / 256, 256, 0, stream>>>(w21a, wb21a, 640 * 320);
  cvt_kernel<<<(640 * 640 + 255) / 256, 256, 0, stream>>>(w21b, wb21b, 640 * 640);
  cvt_kernel<<<(640 * 704 + 255) / 256, 256, 0, stream>>>(w10a, wb10a, 640 * 704);
  cvt_kernel<<<(768 * 640 + 255) / 256, 256, 0, stream>>>(w10b, wb10b, 768 * 640);

  knn_small_kernel<<<128, 64, 0, stream>>>(l1_to_l2, l2feat, l1feat, x1);
  gemm_bf16<0><<<5 * 64, 256, 0, stream>>>(wb21a, x1, b21a, g21a, be21a, h1, 640, 320, 8192);
  gemm_bf16<0><<<5 * 64, 256, 0, stream>>>(wb21b, h1, b21b, g21b, be21b, fbuf, 640, 640, 8192);
  knn_big_kernel<<<512, 128, 0, stream>>>(l0_to_l1, fbuf, radar, xcat);
  gemm_bf16<0><<<5 * 256, 256, 0, stream>>>(wb10a, xcat, b10a, g10a, be10a, h2, 640, 704, 32768);
  gemm_bf16<1><<<6 * 256, 256, 0, stream>>>(wb10b, h2, b10b, g10b, be10b, d_out, 768, 640, 32768);
}